// Round 13
// baseline (1297.187 us; speedup 1.0000x reference)
//
#include <hip/hip_runtime.h>
#include <hip/hip_bf16.h>
#include <cstddef>

#define T_LEN 2048
#define H2 256
#define G4 1024   // 4*H2
#define NLBL 32
#define CLS_TAG 0
#define SEP_TAG 31

// ---------------- helpers ----------------

#if defined(__has_builtin)
#if __has_builtin(__builtin_amdgcn_sdot8)
#define HAS_SDOT8 1
#endif
#if __has_builtin(__builtin_amdgcn_rcpf)
#define HAS_RCPF 1
#endif
#if __has_builtin(__builtin_amdgcn_mov_dpp)
#define HAS_MOVDPP 1
#endif
#endif

// int4x8 dot: acc += sum_m sext(a.nib[m]) * sext(b.nib[m])
// Builtin form. r6/r7 triangulation: forced "v" asm constraints and 8-acc ILP
// both null-or-negative; busy/step is ~790cy in every variant -> v_dot8 issues
// at ~4cy/wave64 and the dot work (128 x 4cy = 512cy) is the real floor.
__device__ __forceinline__ void dot8(int& acc, int a, int b) {
#if defined(HAS_SDOT8)
    acc = __builtin_amdgcn_sdot8(a, b, acc, false);
#elif defined(__gfx950__) || defined(__gfx942__) || defined(__gfx90a__)
    asm("v_dot8_i32_i4 %0, %1, %2, %0" : "+v"(acc) : "v"(a), "v"(b));
#else
    #pragma unroll
    for (int m = 0; m < 8; ++m) {
        int av = (a << (28 - 4 * m)) >> 28;
        int bv = (b << (28 - 4 * m)) >> 28;
        acc += av * bv;
    }
#endif
}

// register pin: opaque, non-rematerializable register value.
__device__ __forceinline__ void pin_v(int& x) {
    asm volatile("" : "+v"(x));
}

__device__ __forceinline__ float rcpf(float x) {
#ifdef HAS_RCPF
    return __builtin_amdgcn_rcpf(x);
#else
    return 1.0f / x;
#endif
}

__device__ __forceinline__ float sigf(float x) {
    return rcpf(1.0f + __expf(-x));
}

__device__ __forceinline__ float tanhf_(float x) {
    x = fminf(fmaxf(x, -15.0f), 15.0f);
    float e = __expf(2.0f * x);
    return (e - 1.0f) * rcpf(e + 1.0f);
}

// lane ^ 1 exchange within quad: quad_perm [1,0,3,2] DPP
__device__ __forceinline__ int xchg_xor1(int x) {
#if defined(HAS_MOVDPP)
    return __builtin_amdgcn_mov_dpp(x, 0xB1, 0xF, 0xF, true);
#else
    return __shfl_xor(x, 1, 64);
#endif
}

// ---------------- kernels ----------------

// 1. fused prologue: blocks [0,2048) gather embeddings; blocks [2048,2560)
//    quantize w_hh (one wave per gate-row); block 2560 quantizes h0 (dir =
//    wave index, lanes shuffle within their own wave).
__global__ __launch_bounds__(256) void prep_k(const int* __restrict__ ids,
                                              const float* __restrict__ emb,
                                              float* __restrict__ xbuf,
                                              const float* __restrict__ w_hh_f,
                                              const float* __restrict__ w_hh_b,
                                              unsigned int* __restrict__ wq4,
                                              float* __restrict__ srowP,
                                              const float* __restrict__ h0,
                                              unsigned int* __restrict__ hq0,
                                              float* __restrict__ sh0) {
    const int b = blockIdx.x;
    if (b < T_LEN) {
        // ---- gather ----
        int row = ids[b];
        xbuf[(size_t)b * 256 + threadIdx.x] = emb[(size_t)row * 256 + threadIdx.x];
        return;
    }
    if (b < T_LEN + 512) {
        // ---- quant w_hh: per-row symmetric int4 into UNIT-MAJOR layout:
        // row m (gate g = m>>8, unit u = m&255) -> wq4[((dir*256+u)*4+g)*32+j],
        // dword j = elems 8j..8j+7. One wave per row. ----
        int wave = threadIdx.x >> 6, lane = threadIdx.x & 63;
        int rg = (b - T_LEN) * 4 + wave;             // 0..2047
        int dir = rg >> 10, m = rg & 1023;
        int g = m >> 8, u = m & 255;
        const float* src = (dir ? w_hh_b : w_hh_f) + (size_t)m * H2;
        float4 w4 = ((const float4*)src)[lane];      // elements 4*lane .. 4*lane+3
        float mx = fmaxf(fmaxf(fabsf(w4.x), fabsf(w4.y)), fmaxf(fabsf(w4.z), fabsf(w4.w)));
        #pragma unroll
        for (int off = 32; off; off >>= 1) mx = fmaxf(mx, __shfl_xor(mx, off, 64));
        float s = (mx > 0.0f) ? mx * (1.0f / 7.0f) : 1.0f;
        float inv = (mx > 0.0f) ? 7.0f * rcpf(mx) : 0.0f;
        int q0 = __float2int_rn(w4.x * inv);
        int q1 = __float2int_rn(w4.y * inv);
        int q2 = __float2int_rn(w4.z * inv);
        int q3 = __float2int_rn(w4.w * inv);
        unsigned int half = (unsigned)(q0 & 15) | ((unsigned)(q1 & 15) << 4) |
                            ((unsigned)(q2 & 15) << 8) | ((unsigned)(q3 & 15) << 12);
        unsigned int other = (unsigned int)__shfl_xor((int)half, 1, 64);
        if ((lane & 1) == 0)   // even lane: elems 8d..8d+3 (lo), odd: 8d+4..8d+7
            wq4[(size_t)((dir * 256 + u) * 4 + g) * 32 + (lane >> 1)] = half | (other << 16);
        if (lane == 0) srowP[(dir * 256 + u) * 4 + g] = s;
        return;
    }
    {
        // ---- quant h0 (per-direction scale): dword j = units 8j..8j+7.
        // wave 0 -> dir 0, wave 1 -> dir 1; lanes shuffle within own wave. ----
        int wave = threadIdx.x >> 6, lane = threadIdx.x & 63;
        if (wave >= 2) return;
        int dir = wave;
        float4 h4 = ((const float4*)(h0 + (size_t)dir * H2))[lane];
        float mx = fmaxf(fmaxf(fabsf(h4.x), fabsf(h4.y)), fmaxf(fabsf(h4.z), fabsf(h4.w)));
        #pragma unroll
        for (int off = 32; off; off >>= 1) mx = fmaxf(mx, __shfl_xor(mx, off, 64));
        float s = (mx > 0.0f) ? mx * (1.0f / 7.0f) : 1.0f;
        float inv = (mx > 0.0f) ? 7.0f * rcpf(mx) : 0.0f;
        int q0 = __float2int_rn(h4.x * inv);
        int q1 = __float2int_rn(h4.y * inv);
        int q2 = __float2int_rn(h4.z * inv);
        int q3 = __float2int_rn(h4.w * inv);
        unsigned int half = (unsigned)(q0 & 15) | ((unsigned)(q1 & 15) << 4) |
                            ((unsigned)(q2 & 15) << 8) | ((unsigned)(q3 & 15) << 12);
        unsigned int other = (unsigned int)__shfl_xor((int)half, 1, 64);
        if ((lane & 1) == 0)
            hq0[dir * 32 + (lane >> 1)] = half | (other << 16);
        if (lane == 0) sh0[dir] = s;
    }
}

// 2. xproj GEMM -> PERMUTED output: xprojP[dir][t][u*4+g]
//    v18 (resubmit; r12 was an infra failure, not a kernel signal):
//    128x64 block tile -> 512 blocks = 2 blocks/CU. r11 lesson: the 128x128
//    form (256 blocks, 1 block/CU, 1 wave/SIMD) kept the halved LDS-read
//    count but exposed LDS latency with no occupancy to hide it — neutral
//    vs r8. This keeps the 8-wide row blocking (half the LDS reads per FMA
//    vs r8) AND 2 blocks/CU for latency overlap.
//    Micro-tile: thread owns rows {ty+16i}x8, cols {tx+16j}x4 (STRIDED).
//    Banks: b-read = (tx+16j+kk) mod 32 -> 16 distinct + broadcast; a-read =
//    4-address broadcast; staging = consecutive. Conflict-free ([.][33] pad).
__global__ __launch_bounds__(256) void gemm_xproj_k(const float* __restrict__ xbuf,
                                                    const float* __restrict__ w_ih_f,
                                                    const float* __restrict__ w_ih_b,
                                                    const float* __restrict__ b_f,
                                                    const float* __restrict__ b_b,
                                                    float* __restrict__ xprojP) {
    __shared__ float As[128][33];
    __shared__ float Bs[64][33];
    int tid = threadIdx.x;
    int t0 = blockIdx.x * 128;
    int n0 = blockIdx.y * 64;
    int tx = tid & 15, ty = tid >> 4;
    float acc[8][4] = {};
    for (int k0 = 0; k0 < 256; k0 += 32) {
        #pragma unroll
        for (int i = 0; i < 16; ++i) {
            int idx = tid + i * 256;
            int r = idx >> 5, kk = idx & 31;
            As[r][kk] = xbuf[(size_t)(t0 + r) * 256 + k0 + kk];
        }
        #pragma unroll
        for (int i = 0; i < 8; ++i) {
            int idx = tid + i * 256;
            int r = idx >> 5, kk = idx & 31;
            int nn = n0 + r;
            const float* wsrc = (nn < 1024) ? (w_ih_f + (size_t)nn * 256)
                                            : (w_ih_b + (size_t)(nn - 1024) * 256);
            Bs[r][kk] = wsrc[k0 + kk];
        }
        __syncthreads();
        #pragma unroll 4
        for (int kk = 0; kk < 32; ++kk) {
            float a[8], b[4];
            #pragma unroll
            for (int i = 0; i < 8; ++i) a[i] = As[ty + 16 * i][kk];
            #pragma unroll
            for (int j = 0; j < 4; ++j) b[j] = Bs[tx + 16 * j][kk];
            #pragma unroll
            for (int i = 0; i < 8; ++i)
                #pragma unroll
                for (int j = 0; j < 4; ++j) acc[i][j] += a[i] * b[j];
        }
        __syncthreads();
    }
    #pragma unroll
    for (int j = 0; j < 4; ++j) {
        int nn = n0 + tx + 16 * j;
        int dir = nn >> 10, nl = nn & 1023;
        float bias = dir ? b_b[nl] : b_f[nl];
        int pidx = (nl & 255) * 4 + (nl >> 8);
        #pragma unroll
        for (int i = 0; i < 8; ++i) {
            int t = t0 + ty + 16 * i;
            xprojP[((size_t)dir * T_LEN + t) * G4 + pidx] = acc[i][j] + bias;
        }
    }
}

// 3. LSTM recurrence v15 (unchanged from r9/r10/r11: ~976us measured, best):
//    v14 structure (peel + pointer-walk + static buf idx + reads-first) +
//    byte publish + early hs store. Relaxed barrier: lgkmcnt(0)-only +
//    s_barrier builtin + sched_barrier(0); vmcnt untouched -> xproj prefetch
//    + hs store stay in flight across the barrier.
__global__ __launch_bounds__(256, 1) void lstm_rec_k(const unsigned int* __restrict__ wq4,
                                                     const float* __restrict__ srowP,
                                                     const float* __restrict__ xprojP,
                                                     const unsigned int* __restrict__ hq0,
                                                     const float* __restrict__ sh0v,
                                                     const float* __restrict__ c0,
                                                     float* __restrict__ hs) {
    const int dir = blockIdx.x;
    const int u = threadIdx.x;            // unit 0..255
    __shared__ __align__(16) unsigned int hqs[2][32];   // 256 units x 4-bit, ping-pong

    // 4 gate rows x 32 int4-dwords, pinned into registers
    int w0[32], w1[32], w2[32], w3[32];
    {
        const unsigned int* wr = wq4 + (size_t)(dir * 256 + u) * 128;
        #pragma unroll
        for (int j = 0; j < 32; ++j) { w0[j] = (int)wr[j];      pin_v(w0[j]); }
        #pragma unroll
        for (int j = 0; j < 32; ++j) { w1[j] = (int)wr[32 + j]; pin_v(w1[j]); }
        #pragma unroll
        for (int j = 0; j < 32; ++j) { w2[j] = (int)wr[64 + j]; pin_v(w2[j]); }
        #pragma unroll
        for (int j = 0; j < 32; ++j) { w3[j] = (int)wr[96 + j]; pin_v(w3[j]); }
    }
    float4 sr4 = ((const float4*)srowP)[dir * 256 + u];
    float sh0 = sh0v[dir];
    float c = c0[dir * H2 + u];
    const float4* xp4 = (const float4*)(xprojP + (size_t)dir * T_LEN * G4);

    // steady-state scale (s_row * 1/7); step-0 scale uses sh0
    float4 scS = make_float4(sr4.x * (1.0f / 7.0f), sr4.y * (1.0f / 7.0f),
                             sr4.z * (1.0f / 7.0f), sr4.w * (1.0f / 7.0f));
    float4 scA = make_float4(sr4.x * sh0, sr4.y * sh0, sr4.z * sh0, sr4.w * sh0);

    if (u < 32) hqs[0][u] = hq0[dir * 32 + u];

    const int stp = dir ? -1 : 1;
    const int ts0 = dir ? (T_LEN - 1) : 0;
    const long zstep = (long)stp * 256;   // float4 elements per t step
    const long hstep = (long)stp * 512;   // floats per t step

    const float4* pz = xp4 + (size_t)ts0 * 256 + u;   // z source for t=ts0
    float4 zx = pz[0];
    float4 zb = pz[zstep];
    const float4* pp = pz + 2 * zstep;                 // prefetch ptr (t = ts0+2*stp)
    float* hp = hs + (size_t)ts0 * 512 + dir * H2 + u; // h store ptr
    __syncthreads();

    auto body = [&](const unsigned int* rdbuf, unsigned int* wrbuf,
                    const float4& sc) __attribute__((always_inline)) {
        // LDS broadcast reads first: 8x ds_read_b128 of the 128B h vector
        int hv[32];
        #pragma unroll
        for (int jq = 0; jq < 8; ++jq) {
            int4 q = ((const int4*)rdbuf)[jq];
            hv[4 * jq + 0] = q.x; hv[4 * jq + 1] = q.y;
            hv[4 * jq + 2] = q.z; hv[4 * jq + 3] = q.w;
        }
        // prefetch s+2 (stays in flight across barriers)
        float4 zc = *pp; pp += zstep;

        int a0 = 0, a1 = 0, a2 = 0, a3 = 0;
        #pragma unroll
        for (int j = 0; j < 32; ++j) {
            dot8(a0, w0[j], hv[j]);
            dot8(a1, w1[j], hv[j]);
            dot8(a2, w2[j], hv[j]);
            dot8(a3, w3[j], hv[j]);
        }
        float zi = zx.x + sc.x * (float)a0;
        float zf = zx.y + sc.y * (float)a1;
        float zg = zx.z + sc.z * (float)a2;
        float zo = zx.w + sc.w * (float)a3;
        float ig = sigf(zi), fg = sigf(zf), gg = tanhf_(zg), og = sigf(zo);
        c = fg * c + ig * gg;
        float h = og * tanhf_(c);
        *hp = h; hp += hstep;                             // fire-and-forget store
        int qv = __float2int_rn(fminf(fmaxf(h * 7.0f, -7.0f), 7.0f));
        int nib = qv & 15;
        int pn = xchg_xor1(nib);                          // neighbor unit's nibble
        if ((u & 1) == 0)                                 // byte u>>1 = units u, u+1
            ((unsigned char*)&wrbuf[0])[u >> 1] =
                (unsigned char)((nib | (pn << 4)) & 255);
        zx = zb; zb = zc;
        // relaxed barrier (verified idiom): wait LDS only, convergent barrier,
        // fence the scheduler. vmem (prefetch + hs store) stays in flight.
        asm volatile("s_waitcnt lgkmcnt(0)" ::: "memory");
        __builtin_amdgcn_s_barrier();
        __builtin_amdgcn_sched_barrier(0);
    };

    // peel step 0 (reads buf0 with the h0 scale, writes buf1)
    body(hqs[0], hqs[1], scA);
    // steady loop: 2046 steps in 1023 pairs + final step, static buf idx.
    for (int it = 0; it < 1023; ++it) {
        body(hqs[1], hqs[0], scS);   // odd s
        body(hqs[0], hqs[1], scS);   // even s
    }
    body(hqs[1], hqs[0], scS);       // s = 2047
}

// 4. logits — v18: transposed weight staging (wld2[j][k], row-major over k)
//    so BOTH operands read float4 over k: 512 scalar-LDS-read iterations ->
//    128 b128 iterations (4x fewer LDS insts). Banks: wld2 b128 lane addr
//    j*520+k -> 16 distinct even bank-quads (j=0..15) + broadcast across tq
//    groups; hld b128 -> broadcast (addr independent of j). Conflict-free.
__global__ __launch_bounds__(128) void logits_k(const float* __restrict__ hs,
                                                const float* __restrict__ w_lin,
                                                const float* __restrict__ b_lin,
                                                float* __restrict__ logits) {
    __shared__ float wld2[16][520];
    __shared__ float hld[8][516];
    int tid = threadIdx.x;
    int t0 = blockIdx.x * 8;
    int n0 = blockIdx.y * 16;
    for (int i = tid; i < 16 * 512; i += 128) {
        int j = i >> 9, k = i & 511;
        wld2[j][k] = w_lin[(size_t)(n0 + j) * 512 + k];
    }
    for (int i = tid; i < 8 * 512; i += 128) {
        int tq = i >> 9, k = i & 511;
        hld[tq][k] = hs[(size_t)(t0 + tq) * 512 + k];
    }
    __syncthreads();
    int j = tid & 15, tq = tid >> 4;
    float acc = b_lin[n0 + j];
    #pragma unroll 8
    for (int k = 0; k < 512; k += 4) {
        float4 hv = *(const float4*)&hld[tq][k];
        float4 wv = *(const float4*)&wld2[j][k];
        acc += hv.x * wv.x + hv.y * wv.y + hv.z * wv.z + hv.w * wv.w;
    }
    logits[(size_t)(t0 + tq) * NLBL + n0 + j] = acc;
}

// 5. gold path score
__global__ __launch_bounds__(256) void gold_k(const float* __restrict__ trans,
                                              const int* __restrict__ target,
                                              const float* __restrict__ logits,
                                              float* __restrict__ gold) {
    __shared__ float red[256];
    int tid = threadIdx.x;
    float s = 0.0f;
    for (int t = tid; t < T_LEN; t += 256) {
        int cur = target[t];
        int prev = (t == 0) ? CLS_TAG : target[t - 1];
        s += trans[cur * NLBL + prev] + logits[(size_t)t * NLBL + cur];
    }
    if (tid == 0) s += trans[SEP_TAG * NLBL + target[T_LEN - 1]];
    red[tid] = s;
    __syncthreads();
    for (int st = 128; st; st >>= 1) {
        if (tid < st) red[tid] += red[tid + st];
        __syncthreads();
    }
    if (tid == 0) gold[0] = red[0];
}

// 6a. CRF tree level 0
__global__ __launch_bounds__(1024) void crf_chain0_k(const float* __restrict__ logits,
                                                     const float* __restrict__ trans,
                                                     float* __restrict__ mats) {
    const int tid = threadIdx.x;
    const int n = tid >> 5, p = tid & 31;
    __shared__ float Rl[2][NLBL][NLBL + 1];
    __shared__ float tl[NLBL][NLBL + 1];
    const int t0 = blockIdx.x * 8;
    float e[8];
    #pragma unroll
    for (int s = 0; s < 8; ++s) e[s] = logits[(size_t)(t0 + s) * NLBL + n];
    float myt = trans[n * NLBL + p];
    tl[n][p] = myt;
    __syncthreads();
    float tr[NLBL];
    #pragma unroll
    for (int k = 0; k < NLBL; ++k) tr[k] = tl[n][k];
    Rl[0][n][p] = myt + e[0];
    __syncthreads();
    float rn = 0.0f;
    for (int s = 1; s < 8; ++s) {
        const int cur = (s - 1) & 1, nxt = s & 1;
        float v[NLBL];
        #pragma unroll
        for (int k = 0; k < NLBL; ++k) v[k] = tr[k] + Rl[cur][k][p];
        float m = v[0];
        #pragma unroll
        for (int k = 1; k < NLBL; ++k) m = fmaxf(m, v[k]);
        float sum = 0.0f;
        #pragma unroll
        for (int k = 0; k < NLBL; ++k) sum += __expf(v[k] - m);
        rn = e[s] + m + __logf(sum);
        Rl[nxt][n][p] = rn;
        __syncthreads();
    }
    mats[(size_t)blockIdx.x * 1024 + tid] = rn;
}

// 6b. CRF tree level N
__global__ __launch_bounds__(1024) void crf_chainN_k(const float* __restrict__ min_,
                                                     float* __restrict__ mout,
                                                     int chunk) {
    const int tid = threadIdx.x;
    const int n = tid >> 5, p = tid & 31;
    __shared__ float Rl[2][NLBL][NLBL + 1];
    __shared__ float Al[2][NLBL][NLBL + 1];
    const size_t base = (size_t)blockIdx.x * chunk;
    float rn = min_[base * 1024 + tid];
    Rl[0][n][p] = rn;
    float anext = min_[(base + 1) * 1024 + tid];
    __syncthreads();
    for (int s = 1; s < chunk; ++s) {
        const int cur = (s - 1) & 1, nxt = s & 1;
        Al[nxt][n][p] = anext;
        if (s + 1 < chunk) anext = min_[(base + s + 1) * 1024 + tid];
        __syncthreads();
        float v[NLBL];
        #pragma unroll
        for (int k = 0; k < NLBL; ++k) v[k] = Al[nxt][n][k] + Rl[cur][k][p];
        float m = v[0];
        #pragma unroll
        for (int k = 1; k < NLBL; ++k) m = fmaxf(m, v[k]);
        float sum = 0.0f;
        #pragma unroll
        for (int k = 0; k < NLBL; ++k) sum += __expf(v[k] - m);
        rn = m + __logf(sum);
        Rl[nxt][n][p] = rn;
        __syncthreads();
    }
    mout[(size_t)blockIdx.x * 1024 + tid] = rn;
}

// 6c. CRF finish
__global__ __launch_bounds__(1024) void crf_finish_k(const float* __restrict__ min_,
                                                     const float* __restrict__ trans,
                                                     const float* __restrict__ gold,
                                                     float* __restrict__ out,
                                                     int chunk) {
    const int tid = threadIdx.x;
    const int n = tid >> 5, p = tid & 31;
    __shared__ float Rl[2][NLBL][NLBL + 1];
    __shared__ float Al[2][NLBL][NLBL + 1];
    __shared__ float af[NLBL];
    float rn = min_[tid];
    Rl[0][n][p] = rn;
    float anext = min_[1024 + tid];
    __syncthreads();
    for (int s = 1; s < chunk; ++s) {
        const int cur = (s - 1) & 1, nxt = s & 1;
        Al[nxt][n][p] = anext;
        if (s + 1 < chunk) anext = min_[(size_t)(s + 1) * 1024 + tid];
        __syncthreads();
        float v[NLBL];
        #pragma unroll
        for (int k = 0; k < NLBL; ++k) v[k] = Al[nxt][n][k] + Rl[cur][k][p];
        float m = v[0];
        #pragma unroll
        for (int k = 1; k < NLBL; ++k) m = fmaxf(m, v[k]);
        float sum = 0.0f;
        #pragma unroll
        for (int k = 0; k < NLBL; ++k) sum += __expf(v[k] - m);
        rn = m + __logf(sum);
        Rl[nxt][n][p] = rn;
        __syncthreads();
    }
    float val = rn + ((p == CLS_TAG) ? 0.0f : -10000.0f);
    float m = val;
    #pragma unroll
    for (int off = 16; off; off >>= 1) m = fmaxf(m, __shfl_xor(m, off, 32));
    float esum = __expf(val - m);
    #pragma unroll
    for (int off = 16; off; off >>= 1) esum += __shfl_xor(esum, off, 32);
    if (p == 0) af[n] = m + __logf(esum);
    __syncthreads();
    if (tid < NLBL) {
        float f = af[tid] + trans[SEP_TAG * NLBL + tid];
        float mm = f;
        #pragma unroll
        for (int off = 16; off; off >>= 1) mm = fmaxf(mm, __shfl_xor(mm, off, 32));
        float es = __expf(f - mm);
        #pragma unroll
        for (int off = 16; off; off >>= 1) es += __shfl_xor(es, off, 32);
        if (tid == 0) out[0] = mm + __logf(es) - gold[0];
    }
}

// ---------------- launch ----------------

extern "C" void kernel_launch(void* const* d_in, const int* in_sizes, int n_in,
                              void* d_out, int out_size, void* d_ws, size_t ws_size,
                              hipStream_t stream) {
    const int*   ids     = (const int*)d_in[0];
    const int*   target  = (const int*)d_in[2];
    const float* emb     = (const float*)d_in[3];
    const float* w_ih_f  = (const float*)d_in[4];
    const float* w_hh_f  = (const float*)d_in[5];
    const float* b_f     = (const float*)d_in[6];
    const float* w_ih_b  = (const float*)d_in[7];
    const float* w_hh_b  = (const float*)d_in[8];
    const float* b_b     = (const float*)d_in[9];
    const float* w_lin   = (const float*)d_in[10];
    const float* b_lin   = (const float*)d_in[11];
    const float* trans   = (const float*)d_in[12];
    const float* h0      = (const float*)d_in[13];
    const float* c0      = (const float*)d_in[14];
    float* out = (float*)d_out;

    char* ws = (char*)d_ws;
    size_t off = 0;
    float* xbuf   = (float*)(ws + off); off += (size_t)T_LEN * 256 * 4;       // 2 MB
    float* xprojP = (float*)(ws + off); off += (size_t)2 * T_LEN * G4 * 4;    // 16 MB
    float* hs     = (float*)(ws + off); off += (size_t)T_LEN * 512 * 4;       // 4 MB
    float* logits = (float*)(ws + off); off += (size_t)T_LEN * NLBL * 4;      // 256 KB
    float* srowP  = (float*)(ws + off); off += (size_t)2 * G4 * 4;            // 8 KB
    float* sh0v   = (float*)(ws + off); off += 16;
    float* gold   = (float*)(ws + off); off += 16;
    unsigned int* hq0 = (unsigned int*)(ws + off); off += (size_t)2 * 32 * 4;
    unsigned int* wq4 = (unsigned int*)(ws + off); off += (size_t)2 * G4 * 32 * 4; // 256 KB
    float* mats1 = xbuf;                 // alias xbuf (dead after gemm_xproj)
    float* mats2 = xbuf + 256 * 1024;

    prep_k<<<T_LEN + 512 + 1, 256, 0, stream>>>(ids, emb, xbuf,
                                                w_hh_f, w_hh_b, wq4, srowP,
                                                h0, hq0, sh0v);
    gemm_xproj_k<<<dim3(16, 32), 256, 0, stream>>>(xbuf, w_ih_f, w_ih_b, b_f, b_b, xprojP);
    lstm_rec_k<<<2, 256, 0, stream>>>(wq4, srowP, xprojP, hq0, sh0v, c0, hs);
    logits_k<<<dim3(256, 2), 128, 0, stream>>>(hs, w_lin, b_lin, logits);
    gold_k<<<1, 256, 0, stream>>>(trans, target, logits, gold);
    crf_chain0_k<<<256, 1024, 0, stream>>>(logits, trans, mats1);
    crf_chainN_k<<<16, 1024, 0, stream>>>(mats1, mats2, 16);
    crf_finish_k<<<1, 1024, 0, stream>>>(mats2, trans, gold, out, 16);
}

// Round 14
// 1263.047 us; speedup vs baseline: 1.0270x; 1.0270x over previous
//
#include <hip/hip_runtime.h>
#include <hip/hip_bf16.h>
#include <cstddef>

#define T_LEN 2048
#define H2 256
#define G4 1024   // 4*H2
#define NLBL 32
#define CLS_TAG 0
#define SEP_TAG 31

// ---------------- helpers ----------------

#if defined(__has_builtin)
#if __has_builtin(__builtin_amdgcn_sdot8)
#define HAS_SDOT8 1
#endif
#if __has_builtin(__builtin_amdgcn_rcpf)
#define HAS_RCPF 1
#endif
#if __has_builtin(__builtin_amdgcn_mov_dpp)
#define HAS_MOVDPP 1
#endif
#endif

// int4x8 dot: acc += sum_m sext(a.nib[m]) * sext(b.nib[m])
// Builtin form. r6/r7 triangulation: forced "v" asm constraints and 8-acc ILP
// both null-or-negative; busy/step is ~790cy in every variant -> v_dot8 issues
// at ~4cy/wave64 and the dot work (128 x 4cy = 512cy) is the real floor.
__device__ __forceinline__ void dot8(int& acc, int a, int b) {
#if defined(HAS_SDOT8)
    acc = __builtin_amdgcn_sdot8(a, b, acc, false);
#elif defined(__gfx950__) || defined(__gfx942__) || defined(__gfx90a__)
    asm("v_dot8_i32_i4 %0, %1, %2, %0" : "+v"(acc) : "v"(a), "v"(b));
#else
    #pragma unroll
    for (int m = 0; m < 8; ++m) {
        int av = (a << (28 - 4 * m)) >> 28;
        int bv = (b << (28 - 4 * m)) >> 28;
        acc += av * bv;
    }
#endif
}

// register pin: opaque, non-rematerializable register value.
__device__ __forceinline__ void pin_v(int& x) {
    asm volatile("" : "+v"(x));
}

__device__ __forceinline__ float rcpf(float x) {
#ifdef HAS_RCPF
    return __builtin_amdgcn_rcpf(x);
#else
    return 1.0f / x;
#endif
}

__device__ __forceinline__ float sigf(float x) {
    return rcpf(1.0f + __expf(-x));
}

__device__ __forceinline__ float tanhf_(float x) {
    x = fminf(fmaxf(x, -15.0f), 15.0f);
    float e = __expf(2.0f * x);
    return (e - 1.0f) * rcpf(e + 1.0f);
}

// lane ^ 1 exchange within quad: quad_perm [1,0,3,2] DPP
__device__ __forceinline__ int xchg_xor1(int x) {
#if defined(HAS_MOVDPP)
    return __builtin_amdgcn_mov_dpp(x, 0xB1, 0xF, 0xF, true);
#else
    return __shfl_xor(x, 1, 64);
#endif
}

// ---------------- kernels ----------------

// 1. fused prologue: blocks [0,2048) gather embeddings; blocks [2048,2560)
//    quantize w_hh (one wave per gate-row); block 2560 quantizes h0 (dir =
//    wave index, lanes shuffle within their own wave).
__global__ __launch_bounds__(256) void prep_k(const int* __restrict__ ids,
                                              const float* __restrict__ emb,
                                              float* __restrict__ xbuf,
                                              const float* __restrict__ w_hh_f,
                                              const float* __restrict__ w_hh_b,
                                              unsigned int* __restrict__ wq4,
                                              float* __restrict__ srowP,
                                              const float* __restrict__ h0,
                                              unsigned int* __restrict__ hq0,
                                              float* __restrict__ sh0) {
    const int b = blockIdx.x;
    if (b < T_LEN) {
        // ---- gather ----
        int row = ids[b];
        xbuf[(size_t)b * 256 + threadIdx.x] = emb[(size_t)row * 256 + threadIdx.x];
        return;
    }
    if (b < T_LEN + 512) {
        // ---- quant w_hh: per-row symmetric int4 into UNIT-MAJOR layout:
        // row m (gate g = m>>8, unit u = m&255) -> wq4[((dir*256+u)*4+g)*32+j],
        // dword j = elems 8j..8j+7. One wave per row. ----
        int wave = threadIdx.x >> 6, lane = threadIdx.x & 63;
        int rg = (b - T_LEN) * 4 + wave;             // 0..2047
        int dir = rg >> 10, m = rg & 1023;
        int g = m >> 8, u = m & 255;
        const float* src = (dir ? w_hh_b : w_hh_f) + (size_t)m * H2;
        float4 w4 = ((const float4*)src)[lane];      // elements 4*lane .. 4*lane+3
        float mx = fmaxf(fmaxf(fabsf(w4.x), fabsf(w4.y)), fmaxf(fabsf(w4.z), fabsf(w4.w)));
        #pragma unroll
        for (int off = 32; off; off >>= 1) mx = fmaxf(mx, __shfl_xor(mx, off, 64));
        float s = (mx > 0.0f) ? mx * (1.0f / 7.0f) : 1.0f;
        float inv = (mx > 0.0f) ? 7.0f * rcpf(mx) : 0.0f;
        int q0 = __float2int_rn(w4.x * inv);
        int q1 = __float2int_rn(w4.y * inv);
        int q2 = __float2int_rn(w4.z * inv);
        int q3 = __float2int_rn(w4.w * inv);
        unsigned int half = (unsigned)(q0 & 15) | ((unsigned)(q1 & 15) << 4) |
                            ((unsigned)(q2 & 15) << 8) | ((unsigned)(q3 & 15) << 12);
        unsigned int other = (unsigned int)__shfl_xor((int)half, 1, 64);
        if ((lane & 1) == 0)   // even lane: elems 8d..8d+3 (lo), odd: 8d+4..8d+7
            wq4[(size_t)((dir * 256 + u) * 4 + g) * 32 + (lane >> 1)] = half | (other << 16);
        if (lane == 0) srowP[(dir * 256 + u) * 4 + g] = s;
        return;
    }
    {
        // ---- quant h0 (per-direction scale): dword j = units 8j..8j+7.
        // wave 0 -> dir 0, wave 1 -> dir 1; lanes shuffle within own wave. ----
        int wave = threadIdx.x >> 6, lane = threadIdx.x & 63;
        if (wave >= 2) return;
        int dir = wave;
        float4 h4 = ((const float4*)(h0 + (size_t)dir * H2))[lane];
        float mx = fmaxf(fmaxf(fabsf(h4.x), fabsf(h4.y)), fmaxf(fabsf(h4.z), fabsf(h4.w)));
        #pragma unroll
        for (int off = 32; off; off >>= 1) mx = fmaxf(mx, __shfl_xor(mx, off, 64));
        float s = (mx > 0.0f) ? mx * (1.0f / 7.0f) : 1.0f;
        float inv = (mx > 0.0f) ? 7.0f * rcpf(mx) : 0.0f;
        int q0 = __float2int_rn(h4.x * inv);
        int q1 = __float2int_rn(h4.y * inv);
        int q2 = __float2int_rn(h4.z * inv);
        int q3 = __float2int_rn(h4.w * inv);
        unsigned int half = (unsigned)(q0 & 15) | ((unsigned)(q1 & 15) << 4) |
                            ((unsigned)(q2 & 15) << 8) | ((unsigned)(q3 & 15) << 12);
        unsigned int other = (unsigned int)__shfl_xor((int)half, 1, 64);
        if ((lane & 1) == 0)
            hq0[dir * 32 + (lane >> 1)] = half | (other << 16);
        if (lane == 0) sh0[dir] = s;
    }
}

// 2. xproj GEMM -> PERMUTED output: xprojP[dir][t][u*4+g]
//    r11 form EXACTLY (best measured: non-lstm 287us, total 1265.5us):
//    128x128 block tile, 256 threads, 8x8 micro-tile with STRIDED register
//    blocking (thread owns rows {ty+16i}, cols {tx+16j}). Banks: b-read =
//    (tx+16j+kk) mod 32 -> 16 distinct + broadcast; a-read = 4-address
//    broadcast; staging writes = (33r+kk) mod 32 distinct. Conflict-free.
//    r13 falsified the 128x64 2-block/CU variant (+30us) — reverted.
__global__ __launch_bounds__(256) void gemm_xproj_k(const float* __restrict__ xbuf,
                                                    const float* __restrict__ w_ih_f,
                                                    const float* __restrict__ w_ih_b,
                                                    const float* __restrict__ b_f,
                                                    const float* __restrict__ b_b,
                                                    float* __restrict__ xprojP) {
    __shared__ float As[128][33];
    __shared__ float Bs[128][33];
    int tid = threadIdx.x;
    int t0 = blockIdx.x * 128;
    int n0 = blockIdx.y * 128;
    int tx = tid & 15, ty = tid >> 4;
    float acc[8][8] = {};
    for (int k0 = 0; k0 < 256; k0 += 32) {
        #pragma unroll
        for (int i = 0; i < 16; ++i) {
            int idx = tid + i * 256;
            int r = idx >> 5, kk = idx & 31;
            As[r][kk] = xbuf[(size_t)(t0 + r) * 256 + k0 + kk];
            int nn = n0 + r;
            const float* wsrc = (nn < 1024) ? (w_ih_f + (size_t)nn * 256)
                                            : (w_ih_b + (size_t)(nn - 1024) * 256);
            Bs[r][kk] = wsrc[k0 + kk];
        }
        __syncthreads();
        #pragma unroll 4
        for (int kk = 0; kk < 32; ++kk) {
            float a[8], b[8];
            #pragma unroll
            for (int i = 0; i < 8; ++i) a[i] = As[ty + 16 * i][kk];
            #pragma unroll
            for (int j = 0; j < 8; ++j) b[j] = Bs[tx + 16 * j][kk];
            #pragma unroll
            for (int i = 0; i < 8; ++i)
                #pragma unroll
                for (int j = 0; j < 8; ++j) acc[i][j] += a[i] * b[j];
        }
        __syncthreads();
    }
    #pragma unroll
    for (int j = 0; j < 8; ++j) {
        int nn = n0 + tx + 16 * j;
        int dir = nn >> 10, nl = nn & 1023;
        float bias = dir ? b_b[nl] : b_f[nl];
        int pidx = (nl & 255) * 4 + (nl >> 8);
        #pragma unroll
        for (int i = 0; i < 8; ++i) {
            int t = t0 + ty + 16 * i;
            xprojP[((size_t)dir * T_LEN + t) * G4 + pidx] = acc[i][j] + bias;
        }
    }
}

// 3. LSTM recurrence v15 (unchanged since r9: ~974us measured, structural
//    floor — 512cy/step dot8-issue + irreducible stall; 7 reorganization
//    attempts r2-r7 all null/negative). v14 structure (peel + pointer-walk +
//    static buf idx + reads-first) + byte publish + early hs store.
//    Relaxed barrier: lgkmcnt(0)-only + s_barrier builtin + sched_barrier(0);
//    vmcnt untouched -> xproj prefetch + hs store stay in flight.
__global__ __launch_bounds__(256, 1) void lstm_rec_k(const unsigned int* __restrict__ wq4,
                                                     const float* __restrict__ srowP,
                                                     const float* __restrict__ xprojP,
                                                     const unsigned int* __restrict__ hq0,
                                                     const float* __restrict__ sh0v,
                                                     const float* __restrict__ c0,
                                                     float* __restrict__ hs) {
    const int dir = blockIdx.x;
    const int u = threadIdx.x;            // unit 0..255
    __shared__ __align__(16) unsigned int hqs[2][32];   // 256 units x 4-bit, ping-pong

    // 4 gate rows x 32 int4-dwords, pinned into registers
    int w0[32], w1[32], w2[32], w3[32];
    {
        const unsigned int* wr = wq4 + (size_t)(dir * 256 + u) * 128;
        #pragma unroll
        for (int j = 0; j < 32; ++j) { w0[j] = (int)wr[j];      pin_v(w0[j]); }
        #pragma unroll
        for (int j = 0; j < 32; ++j) { w1[j] = (int)wr[32 + j]; pin_v(w1[j]); }
        #pragma unroll
        for (int j = 0; j < 32; ++j) { w2[j] = (int)wr[64 + j]; pin_v(w2[j]); }
        #pragma unroll
        for (int j = 0; j < 32; ++j) { w3[j] = (int)wr[96 + j]; pin_v(w3[j]); }
    }
    float4 sr4 = ((const float4*)srowP)[dir * 256 + u];
    float sh0 = sh0v[dir];
    float c = c0[dir * H2 + u];
    const float4* xp4 = (const float4*)(xprojP + (size_t)dir * T_LEN * G4);

    // steady-state scale (s_row * 1/7); step-0 scale uses sh0
    float4 scS = make_float4(sr4.x * (1.0f / 7.0f), sr4.y * (1.0f / 7.0f),
                             sr4.z * (1.0f / 7.0f), sr4.w * (1.0f / 7.0f));
    float4 scA = make_float4(sr4.x * sh0, sr4.y * sh0, sr4.z * sh0, sr4.w * sh0);

    if (u < 32) hqs[0][u] = hq0[dir * 32 + u];

    const int stp = dir ? -1 : 1;
    const int ts0 = dir ? (T_LEN - 1) : 0;
    const long zstep = (long)stp * 256;   // float4 elements per t step
    const long hstep = (long)stp * 512;   // floats per t step

    const float4* pz = xp4 + (size_t)ts0 * 256 + u;   // z source for t=ts0
    float4 zx = pz[0];
    float4 zb = pz[zstep];
    const float4* pp = pz + 2 * zstep;                 // prefetch ptr (t = ts0+2*stp)
    float* hp = hs + (size_t)ts0 * 512 + dir * H2 + u; // h store ptr
    __syncthreads();

    auto body = [&](const unsigned int* rdbuf, unsigned int* wrbuf,
                    const float4& sc) __attribute__((always_inline)) {
        // LDS broadcast reads first: 8x ds_read_b128 of the 128B h vector
        int hv[32];
        #pragma unroll
        for (int jq = 0; jq < 8; ++jq) {
            int4 q = ((const int4*)rdbuf)[jq];
            hv[4 * jq + 0] = q.x; hv[4 * jq + 1] = q.y;
            hv[4 * jq + 2] = q.z; hv[4 * jq + 3] = q.w;
        }
        // prefetch s+2 (stays in flight across barriers)
        float4 zc = *pp; pp += zstep;

        int a0 = 0, a1 = 0, a2 = 0, a3 = 0;
        #pragma unroll
        for (int j = 0; j < 32; ++j) {
            dot8(a0, w0[j], hv[j]);
            dot8(a1, w1[j], hv[j]);
            dot8(a2, w2[j], hv[j]);
            dot8(a3, w3[j], hv[j]);
        }
        float zi = zx.x + sc.x * (float)a0;
        float zf = zx.y + sc.y * (float)a1;
        float zg = zx.z + sc.z * (float)a2;
        float zo = zx.w + sc.w * (float)a3;
        float ig = sigf(zi), fg = sigf(zf), gg = tanhf_(zg), og = sigf(zo);
        c = fg * c + ig * gg;
        float h = og * tanhf_(c);
        *hp = h; hp += hstep;                             // fire-and-forget store
        int qv = __float2int_rn(fminf(fmaxf(h * 7.0f, -7.0f), 7.0f));
        int nib = qv & 15;
        int pn = xchg_xor1(nib);                          // neighbor unit's nibble
        if ((u & 1) == 0)                                 // byte u>>1 = units u, u+1
            ((unsigned char*)&wrbuf[0])[u >> 1] =
                (unsigned char)((nib | (pn << 4)) & 255);
        zx = zb; zb = zc;
        // relaxed barrier (verified idiom): wait LDS only, convergent barrier,
        // fence the scheduler. vmem (prefetch + hs store) stays in flight.
        asm volatile("s_waitcnt lgkmcnt(0)" ::: "memory");
        __builtin_amdgcn_s_barrier();
        __builtin_amdgcn_sched_barrier(0);
    };

    // peel step 0 (reads buf0 with the h0 scale, writes buf1)
    body(hqs[0], hqs[1], scA);
    // steady loop: 2046 steps in 1023 pairs + final step, static buf idx.
    for (int it = 0; it < 1023; ++it) {
        body(hqs[1], hqs[0], scS);   // odd s
        body(hqs[0], hqs[1], scS);   // even s
    }
    body(hqs[1], hqs[0], scS);       // s = 2047
}

// 4. logits (r11 scalar-read form — r13's vectorized variant was part of a
//    net-negative bundle; reverted to best-measured config)
__global__ __launch_bounds__(128) void logits_k(const float* __restrict__ hs,
                                                const float* __restrict__ w_lin,
                                                const float* __restrict__ b_lin,
                                                float* __restrict__ logits) {
    __shared__ float wldT[512][17];
    __shared__ float hld[8][512];
    int tid = threadIdx.x;
    int t0 = blockIdx.x * 8;
    int n0 = blockIdx.y * 16;
    for (int i = tid; i < 16 * 512; i += 128) {
        int j = i >> 9, k = i & 511;
        wldT[k][j] = w_lin[(size_t)(n0 + j) * 512 + k];
    }
    for (int i = tid; i < 8 * 512; i += 128) {
        int tq = i >> 9, k = i & 511;
        hld[tq][k] = hs[(size_t)(t0 + tq) * 512 + k];
    }
    __syncthreads();
    int j = tid & 15, tq = tid >> 4;
    float acc = b_lin[n0 + j];
    #pragma unroll 8
    for (int k = 0; k < 512; ++k) acc += hld[tq][k] * wldT[k][j];
    logits[(size_t)(t0 + tq) * NLBL + n0 + j] = acc;
}

// 5. gold path score
__global__ __launch_bounds__(256) void gold_k(const float* __restrict__ trans,
                                              const int* __restrict__ target,
                                              const float* __restrict__ logits,
                                              float* __restrict__ gold) {
    __shared__ float red[256];
    int tid = threadIdx.x;
    float s = 0.0f;
    for (int t = tid; t < T_LEN; t += 256) {
        int cur = target[t];
        int prev = (t == 0) ? CLS_TAG : target[t - 1];
        s += trans[cur * NLBL + prev] + logits[(size_t)t * NLBL + cur];
    }
    if (tid == 0) s += trans[SEP_TAG * NLBL + target[T_LEN - 1]];
    red[tid] = s;
    __syncthreads();
    for (int st = 128; st; st >>= 1) {
        if (tid < st) red[tid] += red[tid + st];
        __syncthreads();
    }
    if (tid == 0) gold[0] = red[0];
}

// 6a. CRF tree level 0
__global__ __launch_bounds__(1024) void crf_chain0_k(const float* __restrict__ logits,
                                                     const float* __restrict__ trans,
                                                     float* __restrict__ mats) {
    const int tid = threadIdx.x;
    const int n = tid >> 5, p = tid & 31;
    __shared__ float Rl[2][NLBL][NLBL + 1];
    __shared__ float tl[NLBL][NLBL + 1];
    const int t0 = blockIdx.x * 8;
    float e[8];
    #pragma unroll
    for (int s = 0; s < 8; ++s) e[s] = logits[(size_t)(t0 + s) * NLBL + n];
    float myt = trans[n * NLBL + p];
    tl[n][p] = myt;
    __syncthreads();
    float tr[NLBL];
    #pragma unroll
    for (int k = 0; k < NLBL; ++k) tr[k] = tl[n][k];
    Rl[0][n][p] = myt + e[0];
    __syncthreads();
    float rn = 0.0f;
    for (int s = 1; s < 8; ++s) {
        const int cur = (s - 1) & 1, nxt = s & 1;
        float v[NLBL];
        #pragma unroll
        for (int k = 0; k < NLBL; ++k) v[k] = tr[k] + Rl[cur][k][p];
        float m = v[0];
        #pragma unroll
        for (int k = 1; k < NLBL; ++k) m = fmaxf(m, v[k]);
        float sum = 0.0f;
        #pragma unroll
        for (int k = 0; k < NLBL; ++k) sum += __expf(v[k] - m);
        rn = e[s] + m + __logf(sum);
        Rl[nxt][n][p] = rn;
        __syncthreads();
    }
    mats[(size_t)blockIdx.x * 1024 + tid] = rn;
}

// 6b. CRF tree level N
__global__ __launch_bounds__(1024) void crf_chainN_k(const float* __restrict__ min_,
                                                     float* __restrict__ mout,
                                                     int chunk) {
    const int tid = threadIdx.x;
    const int n = tid >> 5, p = tid & 31;
    __shared__ float Rl[2][NLBL][NLBL + 1];
    __shared__ float Al[2][NLBL][NLBL + 1];
    const size_t base = (size_t)blockIdx.x * chunk;
    float rn = min_[base * 1024 + tid];
    Rl[0][n][p] = rn;
    float anext = min_[(base + 1) * 1024 + tid];
    __syncthreads();
    for (int s = 1; s < chunk; ++s) {
        const int cur = (s - 1) & 1, nxt = s & 1;
        Al[nxt][n][p] = anext;
        if (s + 1 < chunk) anext = min_[(base + s + 1) * 1024 + tid];
        __syncthreads();
        float v[NLBL];
        #pragma unroll
        for (int k = 0; k < NLBL; ++k) v[k] = Al[nxt][n][k] + Rl[cur][k][p];
        float m = v[0];
        #pragma unroll
        for (int k = 1; k < NLBL; ++k) m = fmaxf(m, v[k]);
        float sum = 0.0f;
        #pragma unroll
        for (int k = 0; k < NLBL; ++k) sum += __expf(v[k] - m);
        rn = m + __logf(sum);
        Rl[nxt][n][p] = rn;
        __syncthreads();
    }
    mout[(size_t)blockIdx.x * 1024 + tid] = rn;
}

// 6c. CRF finish
__global__ __launch_bounds__(1024) void crf_finish_k(const float* __restrict__ min_,
                                                     const float* __restrict__ trans,
                                                     const float* __restrict__ gold,
                                                     float* __restrict__ out,
                                                     int chunk) {
    const int tid = threadIdx.x;
    const int n = tid >> 5, p = tid & 31;
    __shared__ float Rl[2][NLBL][NLBL + 1];
    __shared__ float Al[2][NLBL][NLBL + 1];
    __shared__ float af[NLBL];
    float rn = min_[tid];
    Rl[0][n][p] = rn;
    float anext = min_[1024 + tid];
    __syncthreads();
    for (int s = 1; s < chunk; ++s) {
        const int cur = (s - 1) & 1, nxt = s & 1;
        Al[nxt][n][p] = anext;
        if (s + 1 < chunk) anext = min_[(size_t)(s + 1) * 1024 + tid];
        __syncthreads();
        float v[NLBL];
        #pragma unroll
        for (int k = 0; k < NLBL; ++k) v[k] = Al[nxt][n][k] + Rl[cur][k][p];
        float m = v[0];
        #pragma unroll
        for (int k = 1; k < NLBL; ++k) m = fmaxf(m, v[k]);
        float sum = 0.0f;
        #pragma unroll
        for (int k = 0; k < NLBL; ++k) sum += __expf(v[k] - m);
        rn = m + __logf(sum);
        Rl[nxt][n][p] = rn;
        __syncthreads();
    }
    float val = rn + ((p == CLS_TAG) ? 0.0f : -10000.0f);
    float m = val;
    #pragma unroll
    for (int off = 16; off; off >>= 1) m = fmaxf(m, __shfl_xor(m, off, 32));
    float esum = __expf(val - m);
    #pragma unroll
    for (int off = 16; off; off >>= 1) esum += __shfl_xor(esum, off, 32);
    if (p == 0) af[n] = m + __logf(esum);
    __syncthreads();
    if (tid < NLBL) {
        float f = af[tid] + trans[SEP_TAG * NLBL + tid];
        float mm = f;
        #pragma unroll
        for (int off = 16; off; off >>= 1) mm = fmaxf(mm, __shfl_xor(mm, off, 32));
        float es = __expf(f - mm);
        #pragma unroll
        for (int off = 16; off; off >>= 1) es += __shfl_xor(es, off, 32);
        if (tid == 0) out[0] = mm + __logf(es) - gold[0];
    }
}

// ---------------- launch ----------------

extern "C" void kernel_launch(void* const* d_in, const int* in_sizes, int n_in,
                              void* d_out, int out_size, void* d_ws, size_t ws_size,
                              hipStream_t stream) {
    const int*   ids     = (const int*)d_in[0];
    const int*   target  = (const int*)d_in[2];
    const float* emb     = (const float*)d_in[3];
    const float* w_ih_f  = (const float*)d_in[4];
    const float* w_hh_f  = (const float*)d_in[5];
    const float* b_f     = (const float*)d_in[6];
    const float* w_ih_b  = (const float*)d_in[7];
    const float* w_hh_b  = (const float*)d_in[8];
    const float* b_b     = (const float*)d_in[9];
    const float* w_lin   = (const float*)d_in[10];
    const float* b_lin   = (const float*)d_in[11];
    const float* trans   = (const float*)d_in[12];
    const float* h0      = (const float*)d_in[13];
    const float* c0      = (const float*)d_in[14];
    float* out = (float*)d_out;

    char* ws = (char*)d_ws;
    size_t off = 0;
    float* xbuf   = (float*)(ws + off); off += (size_t)T_LEN * 256 * 4;       // 2 MB
    float* xprojP = (float*)(ws + off); off += (size_t)2 * T_LEN * G4 * 4;    // 16 MB
    float* hs     = (float*)(ws + off); off += (size_t)T_LEN * 512 * 4;       // 4 MB
    float* logits = (float*)(ws + off); off += (size_t)T_LEN * NLBL * 4;      // 256 KB
    float* srowP  = (float*)(ws + off); off += (size_t)2 * G4 * 4;            // 8 KB
    float* sh0v   = (float*)(ws + off); off += 16;
    float* gold   = (float*)(ws + off); off += 16;
    unsigned int* hq0 = (unsigned int*)(ws + off); off += (size_t)2 * 32 * 4;
    unsigned int* wq4 = (unsigned int*)(ws + off); off += (size_t)2 * G4 * 32 * 4; // 256 KB
    float* mats1 = xbuf;                 // alias xbuf (dead after gemm_xproj)
    float* mats2 = xbuf + 256 * 1024;

    prep_k<<<T_LEN + 512 + 1, 256, 0, stream>>>(ids, emb, xbuf,
                                                w_hh_f, w_hh_b, wq4, srowP,
                                                h0, hq0, sh0v);
    gemm_xproj_k<<<dim3(16, 16), 256, 0, stream>>>(xbuf, w_ih_f, w_ih_b, b_f, b_b, xprojP);
    lstm_rec_k<<<2, 256, 0, stream>>>(wq4, srowP, xprojP, hq0, sh0v, c0, hs);
    logits_k<<<dim3(256, 2), 128, 0, stream>>>(hs, w_lin, b_lin, logits);
    gold_k<<<1, 256, 0, stream>>>(trans, target, logits, gold);
    crf_chain0_k<<<256, 1024, 0, stream>>>(logits, trans, mats1);
    crf_chainN_k<<<16, 1024, 0, stream>>>(mats1, mats2, 16);
    crf_finish_k<<<1, 1024, 0, stream>>>(mats2, trans, gold, out, 16);
}